// Round 5
// baseline (103.915 us; speedup 1.0000x reference)
//
#include <hip/hip_runtime.h>

typedef float v2f __attribute__((ext_vector_type(2)));
typedef float v4f __attribute__((ext_vector_type(4)));

#define BB 8
#define NN 8192
#define MM 8192
#define SPLIT 32
#define MCHUNK (MM / SPLIT)  // 256 xyz2 points staged per block
#define P 8                  // xyz1 points per thread
#define TPB 128              // threads per block (2 waves)

// ws layout: [0, 8MB) : float pmins[SPLIT][B*N]

// d = bz*wz + ww; d = by*wy + d; d = bx*wx + d   -- forced VOP3P packed fp32
__device__ __forceinline__ v2f pk_dist(v2f bx, v2f by, v2f bz, v2f wx, v2f wy, v2f wz, v2f ww) {
    v2f d;
    asm("v_pk_fma_f32 %0, %1, %2, %3" : "=v"(d) : "v"(bz), "v"(wz), "v"(ww));
    asm("v_pk_fma_f32 %0, %1, %2, %0" : "+v"(d) : "v"(by), "v"(wy));
    asm("v_pk_fma_f32 %0, %1, %2, %0" : "+v"(d) : "v"(bx), "v"(wx));
    return d;
}

__global__ __launch_bounds__(TPB, 4) void chamfer_min(const float* __restrict__ xyz1,
                                                      const float* __restrict__ xyz2,
                                                      float* __restrict__ pmins,
                                                      float* __restrict__ out) {
    if (blockIdx.x == 0 && threadIdx.x == 0) out[0] = 0.0f;  // reduce runs after; safe

    // SoA LDS, broadcast b128 reads (same-address => conflict-free)
    __shared__ float xs[MCHUNK], ys[MCHUNK], zs[MCHUNK], w2[MCHUNK];

    // grid = 2048: low 6 bits = tile over B*N (64 tiles x 1024 pts), high 5 = m-split
    int tile  = blockIdx.x & 63;
    int split = blockIdx.x >> 6;
    int batch = tile >> 3;   // 8 batches
    int nt    = tile & 7;    // 8 tiles of 1024 points per batch
    int g = nt * TPB + threadIdx.x;  // this thread's 8-point group, 0..1023

    // ---- fused pack: stage this split's xyz2 chunk -> LDS SoA ----
    for (int t = threadIdx.x; t < MCHUNK; t += TPB) {
        size_t pj = (size_t)batch * MM + (size_t)split * MCHUNK + t;
        float x = xyz2[pj * 3 + 0];
        float y = xyz2[pj * 3 + 1];
        float z = xyz2[pj * 3 + 2];
        xs[t] = x; ys[t] = y; zs[t] = z;
        w2[t] = fmaf(x, x, fmaf(y, y, z * z));
    }

    // ---- load this thread's 8 xyz1 points (24 floats = 6 float4) ----
    const float4* q = (const float4*)(xyz1 + ((size_t)batch * NN + (size_t)g * P) * 3);
    float f[24];
    float4* f4 = (float4*)f;
#pragma unroll
    for (int t = 0; t < 6; ++t) f4[t] = q[t];

    v2f bx2[P], by2[P], bz2[P], m2[P];
    float x2[P];
#pragma unroll
    for (int p = 0; p < P; ++p) {
        float ax = f[3 * p + 0], ay = f[3 * p + 1], az = f[3 * p + 2];
        x2[p] = fmaf(ax, ax, fmaf(ay, ay, az * az));
        bx2[p] = (v2f){-2.0f * ax, -2.0f * ax};
        by2[p] = (v2f){-2.0f * ay, -2.0f * ay};
        bz2[p] = (v2f){-2.0f * az, -2.0f * az};
        m2[p] = (v2f){1e30f, 1e30f};
    }

    __syncthreads();

    // ---- main loop: 4 j's per iter via SoA b128 reads; forced v_pk_fma_f32 ----
#pragma unroll 2
    for (int j = 0; j < MCHUNK; j += 4) {
        v4f wx = *(const v4f*)&xs[j];
        v4f wy = *(const v4f*)&ys[j];
        v4f wz = *(const v4f*)&zs[j];
        v4f ww = *(const v4f*)&w2[j];
        v2f wxl = {wx.x, wx.y}, wxh = {wx.z, wx.w};
        v2f wyl = {wy.x, wy.y}, wyh = {wy.z, wy.w};
        v2f wzl = {wz.x, wz.y}, wzh = {wz.z, wz.w};
        v2f wwl = {ww.x, ww.y}, wwh = {ww.z, ww.w};
#pragma unroll
        for (int p = 0; p < P; ++p) {
            v2f dl = pk_dist(bx2[p], by2[p], bz2[p], wxl, wyl, wzl, wwl);
            m2[p] = __builtin_elementwise_min(m2[p], dl);
            v2f dh = pk_dist(bx2[p], by2[p], bz2[p], wxh, wyh, wzh, wwh);
            m2[p] = __builtin_elementwise_min(m2[p], dh);
        }
    }

    // ---- epilogue ----
    float r[P];
#pragma unroll
    for (int p = 0; p < P; ++p) r[p] = x2[p] + fminf(m2[p].x, m2[p].y);
    size_t base = (size_t)split * (BB * NN) + (size_t)batch * NN + (size_t)g * P;
    float4* dst = (float4*)(pmins + base);
    dst[0] = ((float4*)r)[0];
    dst[1] = ((float4*)r)[1];
}

__global__ __launch_bounds__(256) void chamfer_reduce(const float* __restrict__ pmins,
                                                      float* __restrict__ out) {
    int i = blockIdx.x * 256 + threadIdx.x;  // grid 256 blocks, 0..65535
    float m = pmins[i];
#pragma unroll
    for (int sp = 1; sp < SPLIT; ++sp)
        m = fminf(m, pmins[(size_t)sp * (BB * NN) + i]);
    float s = m;
#pragma unroll
    for (int off = 32; off > 0; off >>= 1) s += __shfl_down(s, off);
    __shared__ float ls[4];
    int lane = threadIdx.x & 63, wv = threadIdx.x >> 6;
    if (lane == 0) ls[wv] = s;
    __syncthreads();
    if (threadIdx.x == 0) {
        float t = (ls[0] + ls[1]) + (ls[2] + ls[3]);
        atomicAdd(out, t * (1.0f / (float)(BB * NN)));
    }
}

extern "C" void kernel_launch(void* const* d_in, const int* in_sizes, int n_in,
                              void* d_out, int out_size, void* d_ws, size_t ws_size,
                              hipStream_t stream) {
    const float* xyz1 = (const float*)d_in[0];
    const float* xyz2 = (const float*)d_in[1];
    float* out = (float*)d_out;
    float* pmins = (float*)d_ws;

    chamfer_min<<<(BB * NN / (P * TPB)) * SPLIT, TPB, 0, stream>>>(xyz1, xyz2, pmins, out);
    chamfer_reduce<<<(BB * NN) / 256, 256, 0, stream>>>(pmins, out);
}

// Round 6
// 101.790 us; speedup vs baseline: 1.0209x; 1.0209x over previous
//
#include <hip/hip_runtime.h>

typedef float v2f __attribute__((ext_vector_type(2)));

#define BB 8
#define NN 8192
#define MM 8192
#define SPLIT 32
#define MCHUNK (MM / SPLIT)  // 256 xyz2 points per block
#define P 8                  // xyz1 points per thread
#define TPB 256
#define JT 16                // j's per inner iteration (8 pairs)

// ws layout (SoA xyz2 pack + partial mins):
//   [0,       256K) : xs[B*M]
//   [256K,    512K) : ys[B*M]
//   [512K,    768K) : zs[B*M]
//   [768K,   1M  )  : w2[B*M]
//   [1M,     9M  )  : pmins[SPLIT][B*N]
#define ASZ (BB * MM)

__global__ __launch_bounds__(256) void chamfer_pack(const float* __restrict__ xyz2,
                                                    float* __restrict__ xs, float* __restrict__ ys,
                                                    float* __restrict__ zs, float* __restrict__ w2,
                                                    float* __restrict__ out) {
    int idx = blockIdx.x * 256 + threadIdx.x;  // 0 .. B*M-1
    if (idx == 0) out[0] = 0.0f;
    float x = xyz2[idx * 3 + 0];
    float y = xyz2[idx * 3 + 1];
    float z = xyz2[idx * 3 + 2];
    xs[idx] = x; ys[idx] = y; zs[idx] = z;
    w2[idx] = fmaf(x, x, fmaf(y, y, z * z));
}

__global__ __launch_bounds__(TPB, 4) void chamfer_min(const float* __restrict__ xyz1,
                                                      const float* __restrict__ xs,
                                                      const float* __restrict__ ys,
                                                      const float* __restrict__ zs,
                                                      const float* __restrict__ w2,
                                                      float* __restrict__ pmins) {
    // grid = 1024: low 5 bits = tile over B*N (32 tiles x 2048 pts), high 5 = m-split
    int tile  = blockIdx.x & 31;
    int split = blockIdx.x >> 5;
    int batch = tile >> 2;   // 8 batches
    int nt    = tile & 3;    // 4 tiles of 2048 points per batch
    int g = nt * TPB + threadIdx.x;  // this thread's 8-point group, 0..1023

    // ---- load this thread's 8 xyz1 points (24 floats = 6 float4) ----
    const float4* q = (const float4*)(xyz1 + ((size_t)batch * NN + (size_t)g * P) * 3);
    float f[24];
    float4* f4 = (float4*)f;
#pragma unroll
    for (int t = 0; t < 6; ++t) f4[t] = q[t];

    v2f bx2[P], by2[P], bz2[P], m2[P];
    float x2[P];
#pragma unroll
    for (int p = 0; p < P; ++p) {
        float ax = f[3 * p + 0], ay = f[3 * p + 1], az = f[3 * p + 2];
        x2[p] = fmaf(ax, ax, fmaf(ay, ay, az * az));
        bx2[p] = (v2f){-2.0f * ax, -2.0f * ax};
        by2[p] = (v2f){-2.0f * ay, -2.0f * ay};
        bz2[p] = (v2f){-2.0f * az, -2.0f * az};
        m2[p] = (v2f){1e30f, 1e30f};
    }

    // wave-uniform base into the SoA arrays
    int base_u = batch * MM + split * MCHUNK;

    // ---- main loop: 16 j's per iter, w via merged s_loads -> SGPR pairs ----
#pragma unroll 1
    for (int j0 = 0; j0 < MCHUNK; j0 += JT) {
        v2f wxp[JT / 2], wyp[JT / 2], wzp[JT / 2], wwp[JT / 2];
#pragma unroll
        for (int t = 0; t < JT / 2; ++t) {
            int o = base_u + j0 + 2 * t;
            wxp[t] = *(const v2f*)(xs + o);
            wyp[t] = *(const v2f*)(ys + o);
            wzp[t] = *(const v2f*)(zs + o);
            wwp[t] = *(const v2f*)(w2 + o);
        }
#pragma unroll
        for (int t = 0; t < JT / 2; ++t) {
            v2f wwv = wwp[t];  // SGPR->VGPR pair once per j-pair (avoids 2-SGPR-read fma)
#pragma unroll
            for (int p = 0; p < P; ++p) {
                v2f d;
                asm("v_pk_fma_f32 %0, %1, %2, %3" : "=v"(d) : "v"(bz2[p]), "s"(wzp[t]), "v"(wwv));
                asm("v_pk_fma_f32 %0, %1, %2, %0" : "+v"(d) : "v"(by2[p]), "s"(wyp[t]));
                asm("v_pk_fma_f32 %0, %1, %2, %0" : "+v"(d) : "v"(bx2[p]), "s"(wxp[t]));
                m2[p] = __builtin_elementwise_min(m2[p], d);
            }
        }
    }

    // ---- epilogue ----
    float r[P];
#pragma unroll
    for (int p = 0; p < P; ++p) r[p] = x2[p] + fminf(m2[p].x, m2[p].y);
    size_t base = (size_t)split * (BB * NN) + (size_t)batch * NN + (size_t)g * P;
    float4* dst = (float4*)(pmins + base);
    dst[0] = ((float4*)r)[0];
    dst[1] = ((float4*)r)[1];
}

__global__ __launch_bounds__(256) void chamfer_reduce(const float* __restrict__ pmins,
                                                      float* __restrict__ out) {
    int i = blockIdx.x * 256 + threadIdx.x;  // grid 256 blocks, 0..65535
    float m = pmins[i];
#pragma unroll
    for (int sp = 1; sp < SPLIT; ++sp)
        m = fminf(m, pmins[(size_t)sp * (BB * NN) + i]);
    float s = m;
#pragma unroll
    for (int off = 32; off > 0; off >>= 1) s += __shfl_down(s, off);
    __shared__ float ls[4];
    int lane = threadIdx.x & 63, wv = threadIdx.x >> 6;
    if (lane == 0) ls[wv] = s;
    __syncthreads();
    if (threadIdx.x == 0) {
        float t = (ls[0] + ls[1]) + (ls[2] + ls[3]);
        atomicAdd(out, t * (1.0f / (float)(BB * NN)));
    }
}

extern "C" void kernel_launch(void* const* d_in, const int* in_sizes, int n_in,
                              void* d_out, int out_size, void* d_ws, size_t ws_size,
                              hipStream_t stream) {
    const float* xyz1 = (const float*)d_in[0];
    const float* xyz2 = (const float*)d_in[1];
    float* out = (float*)d_out;
    float* xs = (float*)d_ws;
    float* ys = xs + ASZ;
    float* zs = ys + ASZ;
    float* w2 = zs + ASZ;
    float* pmins = w2 + ASZ;

    chamfer_pack<<<(BB * MM) / 256, 256, 0, stream>>>(xyz2, xs, ys, zs, w2, out);
    chamfer_min<<<(BB * NN / (P * TPB)) * SPLIT, TPB, 0, stream>>>(xyz1, xs, ys, zs, w2, pmins);
    chamfer_reduce<<<(BB * NN) / 256, 256, 0, stream>>>(pmins, out);
}